// Round 6
// baseline (625.838 us; speedup 1.0000x reference)
//
#include <hip/hip_runtime.h>
#include <hip/hip_fp16.h>

// SparseConvTransposeBlock, round 14: single-writer bucket + plain-LDS merge.
//
// R13 verdict: global fp16 atomics write through to HBM per-op (WRITE 271MB
// identical clustered vs not). But R13's structure gives block b EXCLUSIVE
// ownership of bucket b's rows -> no atomics needed. New k_bucket_lds:
// stage MFMA tiles to per-wave scratch, then merge into a 32KB fp32 LDS
// bucket image with plain ds read-add-write. Races handled structurally:
//  - inter-wave: wave w merges only rows with rr&3==w (disjoint addresses)
//  - intra-wave: one staged row per step, program order (may-alias LDS RMW
//    is order-preserved)
//  - stage/merge separated by __syncthreads rounds.
// Output written once, linearly, fp32 (51MB vs 270MB atomic write-through).
// BN stats fused from LDS. LDS *atomics* (58cy/op, R12) not used anywhere.
//
// Fallbacks: R6 fp16-atomic path, then R1 fp32 path.

#define C_DIM 64
#define LDS_STRIDE 72   // bf16 elems per Wt row: 64 + 8 pad
#define ROW_STRIDE 68   // fp32 elems per scratch row: 64 + 4 pad

#define BUCKET_BITS 7                 // 128 output rows per bucket
#define BUCKET_ROWS (1 << BUCKET_BITS)
#define BIN_CAP 128                   // entries per (k,bucket) bin

typedef __bf16 bf16_t;
typedef bf16_t bf16x4 __attribute__((ext_vector_type(4)));
typedef bf16_t bf16x8 __attribute__((ext_vector_type(8)));
typedef float floatx4 __attribute__((ext_vector_type(4)));

// ---------------------------------------------- features f32 -> bf16 table
__global__ __launch_bounds__(256)
void k_fprep(const float* __restrict__ f, bf16_t* __restrict__ fb, int total4)
{
    int i = blockIdx.x * 256 + threadIdx.x;
    if (i < total4) {
        float4 v = ((const float4*)f)[i];
        bf16x4 o;
        o[0] = (bf16_t)v.x; o[1] = (bf16_t)v.y;
        o[2] = (bf16_t)v.z; o[3] = (bf16_t)v.w;
        ((bf16x4*)fb)[i] = o;
    }
}

// ------------- W -> per-lane MFMA B-fragment layout (bf16), 128B per lane.
// wp[k][lane][(ks*4+nt)*8 + j] = W[k][quad*8+j+32*ks][col+16*nt]   (proven R9+)
__global__ __launch_bounds__(64)
void w_prep(const float* __restrict__ w, bf16_t* __restrict__ wp)
{
    int k = blockIdx.x;
    int lane = threadIdx.x;
    int quad = lane >> 4, col = lane & 15;
    const float* Wk = w + (size_t)k * C_DIM * C_DIM;
    bf16_t* dst = wp + ((size_t)(k * 64 + lane)) * 64;
    #pragma unroll
    for (int ks = 0; ks < 2; ++ks)
        #pragma unroll
        for (int nt = 0; nt < 4; ++nt)
            #pragma unroll
            for (int j = 0; j < 8; ++j)
                dst[(ks * 4 + nt) * 8 + j] =
                    (bf16_t)Wk[(quad * 8 + j + 32 * ks) * C_DIM + col + 16 * nt];
}

// ------------- binning (proven R9+): entry = in_idx[16:0] | row_local<<17
__global__ __launch_bounds__(256)
void b_reorder(const int* __restrict__ pin, const int* __restrict__ pout,
               int* __restrict__ cnt, unsigned* __restrict__ entries,
               int P, int NB)
{
    int k = blockIdx.y;
    int i = blockIdx.x * 256 + threadIdx.x;
    if (i >= P) return;
    int o  = pout[(size_t)k * P + i];
    int in = pin [(size_t)k * P + i];
    int bin = k * NB + (o >> BUCKET_BITS);
    int pos = atomicAdd(&cnt[bin], 1);
    if (pos < BIN_CAP)
        entries[((size_t)bin << BUCKET_BITS) + pos] =
            (unsigned)in | ((unsigned)(o & (BUCKET_ROWS - 1)) << 17);
}

// ------------- main: block b owns bucket b. Per k-bin, rounds of
// {stage 4 tiles -> barrier -> merge into LDS image -> barrier}.
// Epilogue: linear fp32 writeout + fused BN partial stats.
__global__ __launch_bounds__(256)
void k_bucket_lds(const bf16_t* __restrict__ fb, const bf16_t* __restrict__ wp,
                  const int* __restrict__ cnt, const unsigned* __restrict__ entries,
                  float* __restrict__ out, float* __restrict__ sums,
                  int NB, int n_out, int K3)
{
    __shared__ float accs[BUCKET_ROWS * C_DIM];           // 32 KB bucket image
    __shared__ float scratch[4][16 * ROW_STRIDE];         // 17.4 KB stage
    __shared__ __align__(16) unsigned char rr_s[64];      // staged row targets

    const int tid  = threadIdx.x;
    const int wave = tid >> 6;
    const int lane = tid & 63;
    const int quad = lane >> 4;
    const int col  = lane & 15;
    const int b    = blockIdx.x;
    const int row0 = b << BUCKET_BITS;
    float* ls = &scratch[wave][0];

    for (int i = tid; i < BUCKET_ROWS * C_DIM; i += 256) accs[i] = 0.f;
    __syncthreads();

    for (int k = 0; k < K3; ++k) {
        int bin = k * NB + b;
        int n = min(cnt[bin], BIN_CAP);
        if (n <= 0) continue;                       // uniform across block
        int ntile = (n + 15) >> 4;

        // per-lane B fragments for this k (221KB table, L2-hot)
        const bf16_t* wpk = wp + ((size_t)(k * 64 + lane)) * 64;
        bf16x8 bf[2][4];
        #pragma unroll
        for (int ks = 0; ks < 2; ++ks)
            #pragma unroll
            for (int nt = 0; nt < 4; ++nt)
                bf[ks][nt] = *(const bf16x8*)(wpk + (ks * 4 + nt) * 8);

        const unsigned* ebase = entries + ((size_t)bin << BUCKET_BITS);
        int rounds = (ntile + 3) >> 2;
        for (int rd = 0; rd < rounds; ++rd) {
            int t = rd * 4 + wave;                  // this wave's tile
            int rr_own = 255;                       // 255 = invalid slot
            if (t < ntile) {                        // uniform per wave
                int tbase = t * 16;
                unsigned eown = ebase[min(tbase + col, n - 1)];
                int in = (int)(eown & 0x1FFFFu);
                if (tbase + col < n)
                    rr_own = (int)((eown >> 17) & 127u);

                const bf16_t* src = fb + ((size_t)in << 6) + quad * 8;
                bf16x8 a0 = *(const bf16x8*)(src);
                bf16x8 a1 = *(const bf16x8*)(src + 32);

                floatx4 c0 = {0.f,0.f,0.f,0.f}, c1 = {0.f,0.f,0.f,0.f};
                floatx4 c2 = {0.f,0.f,0.f,0.f}, c3 = {0.f,0.f,0.f,0.f};
                c0 = __builtin_amdgcn_mfma_f32_16x16x32_bf16(a0, bf[0][0], c0, 0, 0, 0);
                c0 = __builtin_amdgcn_mfma_f32_16x16x32_bf16(a1, bf[1][0], c0, 0, 0, 0);
                c1 = __builtin_amdgcn_mfma_f32_16x16x32_bf16(a0, bf[0][1], c1, 0, 0, 0);
                c1 = __builtin_amdgcn_mfma_f32_16x16x32_bf16(a1, bf[1][1], c1, 0, 0, 0);
                c2 = __builtin_amdgcn_mfma_f32_16x16x32_bf16(a0, bf[0][2], c2, 0, 0, 0);
                c2 = __builtin_amdgcn_mfma_f32_16x16x32_bf16(a1, bf[1][2], c2, 0, 0, 0);
                c3 = __builtin_amdgcn_mfma_f32_16x16x32_bf16(a0, bf[0][3], c3, 0, 0, 0);
                c3 = __builtin_amdgcn_mfma_f32_16x16x32_bf16(a1, bf[1][3], c3, 0, 0, 0);

                // stage C tile: ls[m][ch], m = quad*4+r, ch = col+16j
                #pragma unroll
                for (int r = 0; r < 4; ++r) {
                    int m = quad * 4 + r;
                    ls[m * ROW_STRIDE + col +  0] = c0[r];
                    ls[m * ROW_STRIDE + col + 16] = c1[r];
                    ls[m * ROW_STRIDE + col + 32] = c2[r];
                    ls[m * ROW_STRIDE + col + 48] = c3[r];
                }
            }
            if (quad == 0) rr_s[wave * 16 + col] = (unsigned char)rr_own;
            __syncthreads();

            // ---- merge: wave w owns rows with rr&3==w (disjoint; no races).
            // rr table read once per lane as 4 broadcast b128 loads.
            uint4 r0 = *(const uint4*)&rr_s[0];
            uint4 r1 = *(const uint4*)&rr_s[16];
            uint4 r2 = *(const uint4*)&rr_s[32];
            uint4 r3 = *(const uint4*)&rr_s[48];
            unsigned rrw[16] = {r0.x, r0.y, r0.z, r0.w, r1.x, r1.y, r1.z, r1.w,
                                r2.x, r2.y, r2.z, r2.w, r3.x, r3.y, r3.z, r3.w};
            #pragma unroll
            for (int w = 0; w < 16; ++w) {
                unsigned sw = (unsigned)__builtin_amdgcn_readfirstlane((int)rrw[w]);
                #pragma unroll
                for (int bs = 0; bs < 4; ++bs) {
                    int m  = w * 4 + bs;
                    int rr = (int)((sw >> (bs * 8)) & 255u);
                    if (rr < 128 && (rr & 3) == wave) {
                        float v = scratch[m >> 4][(m & 15) * ROW_STRIDE + lane];
                        accs[rr * C_DIM + lane] += v;
                    }
                }
            }
            __syncthreads();
        }
    }

    // ---- epilogue: linear fp32 writeout + fused BN partial stats ----
    const int ch = tid & 63;
    const int rg = tid >> 6;
    float s = 0.f, q = 0.f;
    for (int r = rg; r < BUCKET_ROWS; r += 4) {
        int gr = row0 + r;
        if (gr < n_out) {
            float v = accs[r * C_DIM + ch];
            s += v; q += v * v;
            out[((size_t)gr << 6) + ch] = v;
        }
    }
    float* red = &scratch[0][0];      // >=256 floats; safe after last barrier
    __syncthreads();
    red[tid] = s;
    __syncthreads();
    if (tid < 64) {
        float t = red[tid] + red[tid + 64] + red[tid + 128] + red[tid + 192];
        unsafeAtomicAdd(&sums[tid], t);
    }
    __syncthreads();
    red[tid] = q;
    __syncthreads();
    if (tid < 64) {
        float t = red[tid] + red[tid + 64] + red[tid + 128] + red[tid + 192];
        unsafeAtomicAdd(&sums[64 + tid], t);
    }
}

// ------------------------- BN normalize + ReLU: fp32 in-place (proven R1)
__global__ __launch_bounds__(256)
void k3_bn_relu(float* __restrict__ out, const float* __restrict__ sums,
                const float* __restrict__ gamma, const float* __restrict__ beta,
                int n_rows)
{
    int tid = blockIdx.x * 256 + threadIdx.x;
    int ch0 = (tid * 4) & 63;
    float inv_n = 1.0f / (float)n_rows;
    float sc[4], sh[4];
    #pragma unroll
    for (int j = 0; j < 4; ++j) {
        int ch    = ch0 + j;
        float m   = sums[ch] * inv_n;
        float var = sums[64 + ch] * inv_n - m * m;
        float inv = rsqrtf(var + 1e-5f);
        float g   = gamma[ch] * inv;
        sc[j] = g;
        sh[j] = beta[ch] - m * g;
    }
    size_t total = (size_t)n_rows * C_DIM / 4;
    for (size_t i = tid; i < total; i += (size_t)gridDim.x * 256) {
        float4 v = ((const float4*)out)[i];
        v.x = fmaxf(v.x * sc[0] + sh[0], 0.f);
        v.y = fmaxf(v.y * sc[1] + sh[1], 0.f);
        v.z = fmaxf(v.z * sc[2] + sh[2], 0.f);
        v.w = fmaxf(v.w * sc[3] + sh[3], 0.f);
        ((float4*)out)[i] = v;
    }
}

// ======================= R6 main kernel (proven fallback) ===================
__global__ __launch_bounds__(256)
void k1_fp16(const float* __restrict__ features,
             const bf16_t* __restrict__ fbf16,
             const float* __restrict__ weight,
             const int* __restrict__ pairs_in,
             const int* __restrict__ pairs_out,
             __half* __restrict__ acc,
             int P, int rows_per_block, int use_bf16)
{
    __shared__ bf16_t Wt[C_DIM * LDS_STRIDE];
    __shared__ float  scratch[4][16 * ROW_STRIDE];

    const int k   = blockIdx.y;
    const int tid = threadIdx.x;

    const float* Wk = weight + (size_t)k * C_DIM * C_DIM;
    for (int i = tid; i < C_DIM * C_DIM; i += 256) {
        int c = i >> 6, d = i & 63;
        Wt[d * LDS_STRIDE + c] = (bf16_t)Wk[i];
    }
    __syncthreads();

    const int wave = tid >> 6;
    const int lane = tid & 63;
    const int quad = lane >> 4;
    const int col  = lane & 15;
    const int sub  = lane >> 5;
    const int c2   = lane & 31;
    float* ls = &scratch[wave][0];

    bf16x8 bfrag[2][4];
    #pragma unroll
    for (int ks = 0; ks < 2; ++ks)
        #pragma unroll
        for (int nt = 0; nt < 4; ++nt)
            bfrag[ks][nt] =
                *(const bf16x8*)&Wt[(col + 16 * nt) * LDS_STRIDE + quad * 8 + 32 * ks];

    const int* __restrict__ pin  = pairs_in  + (size_t)k * P;
    const int* __restrict__ pout = pairs_out + (size_t)k * P;

    const int p0   = blockIdx.x * rows_per_block;
    const int pend = min(p0 + rows_per_block, P);

    for (int base = p0 + wave * 16; base < pend; base += 64) {
        int prow    = base + col;
        int clamped = (prow < pend) ? prow : (pend - 1);
        int in_idx  = pin[clamped];
        int out_idx = pout[clamped];

        bf16x8 a0, a1;
        if (use_bf16) {
            const bf16_t* src = fbf16 + (size_t)in_idx * C_DIM + quad * 8;
            a0 = *(const bf16x8*)(src);
            a1 = *(const bf16x8*)(src + 32);
        } else {
            const float* src = features + (size_t)in_idx * C_DIM + quad * 8;
            float4 f0 = *(const float4*)(src);
            float4 f1 = *(const float4*)(src + 4);
            float4 f2 = *(const float4*)(src + 32);
            float4 f3 = *(const float4*)(src + 36);
            a0[0] = (bf16_t)f0.x; a0[1] = (bf16_t)f0.y; a0[2] = (bf16_t)f0.z; a0[3] = (bf16_t)f0.w;
            a0[4] = (bf16_t)f1.x; a0[5] = (bf16_t)f1.y; a0[6] = (bf16_t)f1.z; a0[7] = (bf16_t)f1.w;
            a1[0] = (bf16_t)f2.x; a1[1] = (bf16_t)f2.y; a1[2] = (bf16_t)f2.z; a1[3] = (bf16_t)f2.w;
            a1[4] = (bf16_t)f3.x; a1[5] = (bf16_t)f3.y; a1[6] = (bf16_t)f3.z; a1[7] = (bf16_t)f3.w;
        }

        floatx4 acc0 = {0.f, 0.f, 0.f, 0.f};
        floatx4 acc1 = {0.f, 0.f, 0.f, 0.f};
        floatx4 acc2 = {0.f, 0.f, 0.f, 0.f};
        floatx4 acc3 = {0.f, 0.f, 0.f, 0.f};

        acc0 = __builtin_amdgcn_mfma_f32_16x16x32_bf16(a0, bfrag[0][0], acc0, 0, 0, 0);
        acc0 = __builtin_amdgcn_mfma_f32_16x16x32_bf16(a1, bfrag[1][0], acc0, 0, 0, 0);
        acc1 = __builtin_amdgcn_mfma_f32_16x16x32_bf16(a0, bfrag[0][1], acc1, 0, 0, 0);
        acc1 = __builtin_amdgcn_mfma_f32_16x16x32_bf16(a1, bfrag[1][1], acc1, 0, 0, 0);
        acc2 = __builtin_amdgcn_mfma_f32_16x16x32_bf16(a0, bfrag[0][2], acc2, 0, 0, 0);
        acc2 = __builtin_amdgcn_mfma_f32_16x16x32_bf16(a1, bfrag[1][2], acc2, 0, 0, 0);
        acc3 = __builtin_amdgcn_mfma_f32_16x16x32_bf16(a0, bfrag[0][3], acc3, 0, 0, 0);
        acc3 = __builtin_amdgcn_mfma_f32_16x16x32_bf16(a1, bfrag[1][3], acc3, 0, 0, 0);

        #pragma unroll
        for (int r = 0; r < 4; ++r) {
            int m = quad * 4 + r;
            ls[m * ROW_STRIDE + col +  0] = acc0[r];
            ls[m * ROW_STRIDE + col + 16] = acc1[r];
            ls[m * ROW_STRIDE + col + 32] = acc2[r];
            ls[m * ROW_STRIDE + col + 48] = acc3[r];
        }
        asm volatile("s_waitcnt lgkmcnt(0)" ::: "memory");

        #pragma unroll
        for (int m2 = 0; m2 < 8; ++m2) {
            int m = m2 * 2 + sub;
            float2 v = *(const float2*)&ls[m * ROW_STRIDE + 2 * c2];
            __half2 h = __floats2half2_rn(v.x, v.y);
            int g = __shfl(out_idx, m);
            if (base + m < pend)
                unsafeAtomicAdd((__half2*)(acc + (size_t)g * C_DIM + 2 * c2), h);
        }
    }
}

__global__ __launch_bounds__(256)
void k2_stats_h(const __half* __restrict__ acc, float* __restrict__ sums,
                int n_rows)
{
    const int tid = threadIdx.x;
    const int c8  = tid & 7;
    const int sub = tid >> 3;

    float s[8] = {0,0,0,0,0,0,0,0}, q[8] = {0,0,0,0,0,0,0,0};
    for (int r = blockIdx.x * 32 + sub; r < n_rows; r += gridDim.x * 32) {
        float4 v = *(const float4*)&acc[(size_t)r * C_DIM + c8 * 8];
        const __half2* h = (const __half2*)&v;
        #pragma unroll
        for (int j = 0; j < 4; ++j) {
            float x = __half2float(h[j].x), y = __half2float(h[j].y);
            s[2*j]   += x; q[2*j]   += x * x;
            s[2*j+1] += y; q[2*j+1] += y * y;
        }
    }

    __shared__ float red[128];
    if (tid < 128) red[tid] = 0.f;
    __syncthreads();
    #pragma unroll
    for (int j = 0; j < 8; ++j) {
        atomicAdd(&red[c8 * 8 + j], s[j]);
        atomicAdd(&red[64 + c8 * 8 + j], q[j]);
    }
    __syncthreads();
    if (tid < 128) atomicAdd(&sums[tid], red[tid]);
}

__global__ __launch_bounds__(256)
void k3_bn_relu_h(const __half* __restrict__ acc, float* __restrict__ out,
                  const float* __restrict__ sums,
                  const float* __restrict__ gamma, const float* __restrict__ beta,
                  int n_rows)
{
    int tid = blockIdx.x * 256 + threadIdx.x;
    int c8  = tid & 7;
    float inv_n = 1.0f / (float)n_rows;

    float sc[8], sh[8];
    #pragma unroll
    for (int j = 0; j < 8; ++j) {
        int ch    = c8 * 8 + j;
        float m   = sums[ch] * inv_n;
        float var = sums[64 + ch] * inv_n - m * m;
        float inv = rsqrtf(var + 1e-5f);
        float g   = gamma[ch] * inv;
        sc[j] = g;
        sh[j] = beta[ch] - m * g;
    }

    size_t total = (size_t)n_rows * 8;
    for (size_t i = tid; i < total; i += (size_t)gridDim.x * 256) {
        float4 v = ((const float4*)acc)[i];
        const __half2* h = (const __half2*)&v;
        float4 o0, o1;
        o0.x = fmaxf(__half2float(h[0].x) * sc[0] + sh[0], 0.f);
        o0.y = fmaxf(__half2float(h[0].y) * sc[1] + sh[1], 0.f);
        o0.z = fmaxf(__half2float(h[1].x) * sc[2] + sh[2], 0.f);
        o0.w = fmaxf(__half2float(h[1].y) * sc[3] + sh[3], 0.f);
        o1.x = fmaxf(__half2float(h[2].x) * sc[4] + sh[4], 0.f);
        o1.y = fmaxf(__half2float(h[2].y) * sc[5] + sh[5], 0.f);
        o1.z = fmaxf(__half2float(h[3].x) * sc[6] + sh[6], 0.f);
        o1.w = fmaxf(__half2float(h[3].y) * sc[7] + sh[7], 0.f);
        ((float4*)out)[2 * i]     = o0;
        ((float4*)out)[2 * i + 1] = o1;
    }
}

// ===================== fallback (R1 path, proven) ===========================
__global__ __launch_bounds__(256)
void k1_scatter_gemm(const float* __restrict__ features,
                     const float* __restrict__ weight,
                     const int* __restrict__ pairs_in,
                     const int* __restrict__ pairs_out,
                     float* __restrict__ out,
                     int P, int rows_per_block)
{
    __shared__ bf16_t Wt[C_DIM * LDS_STRIDE];
    const int k   = blockIdx.y;
    const int tid = threadIdx.x;
    const float* Wk = weight + (size_t)k * C_DIM * C_DIM;
    for (int i = tid; i < C_DIM * C_DIM; i += 256) {
        int c = i >> 6, d = i & 63;
        Wt[d * LDS_STRIDE + c] = (bf16_t)Wk[i];
    }
    __syncthreads();
    const int wave = tid >> 6, lane = tid & 63, quad = lane >> 4, col = lane & 15;
    bf16x8 bfrag[2][4];
    #pragma unroll
    for (int ks = 0; ks < 2; ++ks)
        #pragma unroll
        for (int nt = 0; nt < 4; ++nt)
            bfrag[ks][nt] =
                *(const bf16x8*)&Wt[(col + 16 * nt) * LDS_STRIDE + quad * 8 + 32 * ks];
    const int* __restrict__ pin  = pairs_in  + (size_t)k * P;
    const int* __restrict__ pout = pairs_out + (size_t)k * P;
    const int p0   = blockIdx.x * rows_per_block;
    const int pend = min(p0 + rows_per_block, P);
    for (int base = p0 + wave * 16; base < pend; base += 64) {
        int prow    = base + col;
        int clamped = (prow < pend) ? prow : (pend - 1);
        int in_idx  = pin[clamped];
        int out_idx = pout[clamped];
        const float* src = features + (size_t)in_idx * C_DIM + quad * 8;
        float4 f0 = *(const float4*)(src);
        float4 f1 = *(const float4*)(src + 4);
        float4 f2 = *(const float4*)(src + 32);
        float4 f3 = *(const float4*)(src + 36);
        bf16x8 a0, a1;
        a0[0] = (bf16_t)f0.x; a0[1] = (bf16_t)f0.y; a0[2] = (bf16_t)f0.z; a0[3] = (bf16_t)f0.w;
        a0[4] = (bf16_t)f1.x; a0[5] = (bf16_t)f1.y; a0[6] = (bf16_t)f1.z; a0[7] = (bf16_t)f1.w;
        a1[0] = (bf16_t)f2.x; a1[1] = (bf16_t)f2.y; a1[2] = (bf16_t)f2.z; a1[3] = (bf16_t)f2.w;
        a1[4] = (bf16_t)f3.x; a1[5] = (bf16_t)f3.y; a1[6] = (bf16_t)f3.z; a1[7] = (bf16_t)f3.w;
        floatx4 acc0 = {0.f,0.f,0.f,0.f}, acc1 = {0.f,0.f,0.f,0.f};
        floatx4 acc2 = {0.f,0.f,0.f,0.f}, acc3 = {0.f,0.f,0.f,0.f};
        acc0 = __builtin_amdgcn_mfma_f32_16x16x32_bf16(a0, bfrag[0][0], acc0, 0, 0, 0);
        acc0 = __builtin_amdgcn_mfma_f32_16x16x32_bf16(a1, bfrag[1][0], acc0, 0, 0, 0);
        acc1 = __builtin_amdgcn_mfma_f32_16x16x32_bf16(a0, bfrag[0][1], acc1, 0, 0, 0);
        acc1 = __builtin_amdgcn_mfma_f32_16x16x32_bf16(a1, bfrag[1][1], acc1, 0, 0, 0);
        acc2 = __builtin_amdgcn_mfma_f32_16x16x32_bf16(a0, bfrag[0][2], acc2, 0, 0, 0);
        acc2 = __builtin_amdgcn_mfma_f32_16x16x32_bf16(a1, bfrag[1][2], acc2, 0, 0, 0);
        acc3 = __builtin_amdgcn_mfma_f32_16x16x32_bf16(a0, bfrag[0][3], acc3, 0, 0, 0);
        acc3 = __builtin_amdgcn_mfma_f32_16x16x32_bf16(a1, bfrag[1][3], acc3, 0, 0, 0);
        #pragma unroll
        for (int r = 0; r < 4; ++r) {
            int m = quad * 4 + r;
            int g = __shfl(out_idx, m);
            if (base + m < pend) {
                float* dst = out + (size_t)g * C_DIM + col;
                unsafeAtomicAdd(dst +  0, acc0[r]);
                unsafeAtomicAdd(dst + 16, acc1[r]);
                unsafeAtomicAdd(dst + 32, acc2[r]);
                unsafeAtomicAdd(dst + 48, acc3[r]);
            }
        }
    }
}

__global__ __launch_bounds__(256)
void k2_stats(const float* __restrict__ acc, float* __restrict__ sums, int n_rows)
{
    int tid = threadIdx.x;
    int ch  = tid & 63;
    int sub = tid >> 6;
    float s = 0.f, s2 = 0.f;
    for (int r = blockIdx.x * 4 + sub; r < n_rows; r += gridDim.x * 4) {
        float v = acc[(size_t)r * C_DIM + ch];
        s  += v;
        s2 += v * v;
    }
    __shared__ float red[256];
    red[tid] = s;
    __syncthreads();
    if (tid < 64) {
        float t = red[tid] + red[tid + 64] + red[tid + 128] + red[tid + 192];
        atomicAdd(&sums[ch], t);
    }
    __syncthreads();
    red[tid] = s2;
    __syncthreads();
    if (tid < 64) {
        float t = red[tid] + red[tid + 64] + red[tid + 128] + red[tid + 192];
        atomicAdd(&sums[64 + ch], t);
    }
}

// ============================================================================
extern "C" void kernel_launch(void* const* d_in, const int* in_sizes, int n_in,
                              void* d_out, int out_size, void* d_ws, size_t ws_size,
                              hipStream_t stream)
{
    const float* features  = (const float*)d_in[0];
    const float* weight    = (const float*)d_in[1];
    // d_in[2] = bias (cancels in training-mode BN)
    const float* gamma     = (const float*)d_in[3];
    const float* beta      = (const float*)d_in[4];
    const int*   pairs_in  = (const int*)d_in[5];
    const int*   pairs_out = (const int*)d_in[6];

    const int n_out     = out_size / C_DIM;
    const int n_in_rows = in_sizes[0] / C_DIM;
    const int K3        = in_sizes[1] / (C_DIM * C_DIM);
    const int P         = in_sizes[5] / K3;

    float* out = (float*)d_out;

    // -------- primary workspace: sums(512) | cnt | fb | wp | entries
    const int    NB      = (n_out + BUCKET_ROWS - 1) >> BUCKET_BITS;
    const size_t NBINS   = (size_t)K3 * NB;
    const size_t off_cnt = 512;
    const size_t off_fb  = (off_cnt + NBINS * 4 + 255) & ~(size_t)255;
    const size_t fb_bytes = (size_t)n_in_rows * C_DIM * 2;
    const size_t off_wp  = (off_fb + fb_bytes + 255) & ~(size_t)255;
    const size_t off_en  = (off_wp + (size_t)K3 * C_DIM * C_DIM * 2 + 255) & ~(size_t)255;
    const size_t need_c  = off_en + NBINS * BIN_CAP * 4;

    if (ws_size >= need_c && n_in_rows <= (1 << 17)) {
        float*    sums  = (float*)d_ws;
        int*      cnt   = (int*)((char*)d_ws + off_cnt);
        bf16_t*   fb    = (bf16_t*)((char*)d_ws + off_fb);
        bf16_t*   wpb   = (bf16_t*)((char*)d_ws + off_wp);
        unsigned* ent   = (unsigned*)((char*)d_ws + off_en);

        hipMemsetAsync(d_ws, 0, off_cnt + NBINS * 4, stream);  // sums + cnt
        k_fprep<<<(n_in_rows * 16 + 255) / 256, 256, 0, stream>>>(
            features, fb, n_in_rows * 16);
        w_prep<<<K3, 64, 0, stream>>>(weight, wpb);

        dim3 gr((P + 255) / 256, K3);
        b_reorder<<<gr, 256, 0, stream>>>(pairs_in, pairs_out, cnt, ent, P, NB);

        k_bucket_lds<<<NB, 256, 0, stream>>>(fb, wpb, cnt, ent, out, sums,
                                             NB, n_out, K3);

        k3_bn_relu<<<dim3(1024), 256, 0, stream>>>(out, sums, gamma, beta, n_out);
        return;
    }

    // ---------------- R6 fp16-atomic path (proven fallback) ----------------
    size_t acc_bytes6 = (size_t)n_out * C_DIM * 2;
    size_t off_acc6   = 512;
    size_t off_fb6    = (off_acc6 + acc_bytes6 + 255) & ~(size_t)255;
    size_t fb_bytes6  = (size_t)n_in_rows * C_DIM * 2;
    size_t need_b     = off_acc6 + acc_bytes6;
    size_t need_a     = off_fb6 + fb_bytes6;

    float*  sums  = (float*)d_ws;
    __half* acc   = (__half*)((char*)d_ws + off_acc6);
    bf16_t* fbf16 = (bf16_t*)((char*)d_ws + off_fb6);

    const int rows_per_block = 512;
    dim3 g1((P + rows_per_block - 1) / rows_per_block, K3);

    if (ws_size >= need_b) {
        const int use_bf16 = (ws_size >= need_a) ? 1 : 0;

        hipMemsetAsync(d_ws, 0, off_acc6 + acc_bytes6, stream);
        if (use_bf16)
            k_fprep<<<(n_in_rows * 16 + 255) / 256, 256, 0, stream>>>(
                features, fbf16, n_in_rows * 16);

        k1_fp16<<<g1, 256, 0, stream>>>(features, fbf16, weight, pairs_in,
                                        pairs_out, acc, P, rows_per_block,
                                        use_bf16);

        k2_stats_h<<<dim3(256), 256, 0, stream>>>(acc, sums, n_out);
        k3_bn_relu_h<<<dim3(512), 256, 0, stream>>>(acc, out, sums, gamma,
                                                    beta, n_out);
    } else {
        hipMemsetAsync(d_out, 0, (size_t)out_size * sizeof(float), stream);
        hipMemsetAsync(d_ws, 0, 512, stream);

        k1_scatter_gemm<<<g1, 256, 0, stream>>>(features, weight, pairs_in,
                                                pairs_out, out, P, rows_per_block);
        k2_stats<<<dim3(1024), 256, 0, stream>>>(out, sums, n_out);
        k3_bn_relu<<<dim3(1024), 256, 0, stream>>>(out, sums, gamma, beta, n_out);
    }
}